// Round 1
// baseline (1442.752 us; speedup 1.0000x reference)
//
#include <hip/hip_runtime.h>
#include <stdint.h>

#define NNODES  200000
#define NEDGES  400000
#define NGRAPHS 4000
#define NLAYERS 5
#define BN_EPS  1e-5f

typedef __attribute__((ext_vector_type(8))) short short8;
typedef __attribute__((ext_vector_type(4))) float f32x4;

__device__ __forceinline__ unsigned short f2bf(float f) {
    unsigned int u = __float_as_uint(f);
    return (unsigned short)((u + 0x7fffu + ((u >> 16) & 1u)) >> 16);
}
__device__ __forceinline__ float bf2f(unsigned short b) {
    return __uint_as_float(((unsigned int)b) << 16);
}

// ---------------- graph prep ----------------

__global__ void k_init(int* __restrict__ cnt, int* __restrict__ cursor, float* __restrict__ stats) {
    int i = blockIdx.x * 256 + threadIdx.x;
    if (i < NNODES) { cnt[i] = 0; cursor[i] = 0; }
    if (i < NLAYERS * 256) stats[i] = 0.f;
}

__global__ void k_count(const int* __restrict__ ei, int* __restrict__ cnt) {
    int e = blockIdx.x * 256 + threadIdx.x;
    if (e < NEDGES) atomicAdd(&cnt[ei[NEDGES + e]], 1);
}

__global__ void k_dinv(const int* __restrict__ cnt, float* __restrict__ dinv) {
    int v = blockIdx.x * 256 + threadIdx.x;
    if (v < NNODES) dinv[v] = rsqrtf((float)cnt[v] + 1.0f);
}

__global__ __launch_bounds__(256) void k_scan1(const int* __restrict__ cnt,
                                               int* __restrict__ roff, int* __restrict__ bsum) {
    __shared__ int s[256];
    int t = threadIdx.x;
    int v = blockIdx.x * 256 + t;
    int val = (v < NNODES) ? cnt[v] : 0;
    s[t] = val; __syncthreads();
    int sum = val;
    for (int o = 1; o < 256; o <<= 1) {
        int tmp = (t >= o) ? s[t - o] : 0;
        __syncthreads();
        sum += tmp; s[t] = sum;
        __syncthreads();
    }
    if (v < NNODES) roff[v] = sum - val;       // exclusive within block
    if (t == 255) bsum[blockIdx.x] = s[255];
}

__global__ __launch_bounds__(1024) void k_scan2(int* __restrict__ bsum, int nb) {
    __shared__ int s[1024];
    int t = threadIdx.x;
    int val = (t < nb) ? bsum[t] : 0;
    s[t] = val; __syncthreads();
    int sum = val;
    for (int o = 1; o < 1024; o <<= 1) {
        int tmp = (t >= o) ? s[t - o] : 0;
        __syncthreads();
        sum += tmp; s[t] = sum;
        __syncthreads();
    }
    if (t < nb) bsum[t] = sum - val;           // exclusive block offsets
}

__global__ void k_scan3(int* __restrict__ roff, const int* __restrict__ bsum) {
    int v = blockIdx.x * 256 + threadIdx.x;
    if (v < NNODES) roff[v] += bsum[blockIdx.x];
    if (v == 0) roff[NNODES] = NEDGES;
}

__global__ void k_fill(const int* __restrict__ ei, const float* __restrict__ dinv,
                       const int* __restrict__ roff, int* __restrict__ cursor,
                       int* __restrict__ csrc, float* __restrict__ cw) {
    int e = blockIdx.x * 256 + threadIdx.x;
    if (e >= NEDGES) return;
    int s = ei[e], d = ei[NEDGES + e];
    int pos = atomicAdd(&cursor[d], 1);
    int idx = roff[d] + pos;
    csrc[idx] = s;
    cw[idx] = dinv[s] * dinv[d];
}

__global__ void k_ranges(const int* __restrict__ batch, int* __restrict__ gstart) {
    int v = blockIdx.x * 256 + threadIdx.x;
    if (v >= NNODES) return;
    int b = batch[v];
    if (v == 0) {
        for (int g = 0; g <= b; ++g) gstart[g] = 0;
    } else {
        int pb = batch[v - 1];
        for (int g = pb + 1; g <= b; ++g) gstart[g] = v;
    }
    if (v == NNODES - 1) {
        for (int g = b + 1; g <= NGRAPHS; ++g) gstart[g] = NNODES;
    }
}

// transpose + bf16-convert + LDS-image-swizzle the 5 layer weights: WT[n][k] = W[k][n]
__global__ void k_wtrans(const float* __restrict__ Wg, char* __restrict__ wt) {
    int idx = blockIdx.x * 256 + threadIdx.x;
    if (idx >= NLAYERS * 128 * 128) return;
    int l = idx >> 14;
    int rem = idx & 16383;
    int n = rem >> 7;
    int k = rem & 127;
    float v = Wg[l * 16384 + k * 128 + n];
    char* img = wt + l * 32768;
    *(unsigned short*)(img + (n << 8) + (((k << 1)) ^ ((n & 7) << 4))) = f2bf(v);
}

// ---------------- input projection: h0 = x @ Wx + bx ----------------

__global__ __launch_bounds__(256) void k_inproj(const float* __restrict__ x,
                                                const float* __restrict__ Wx,
                                                const float* __restrict__ bx,
                                                float* __restrict__ h) {
    int c = threadIdx.x & 127;
    int sub = threadIdx.x >> 7;
    float bias = bx[c];
    for (int v = blockIdx.x * 2 + sub; v < NNODES; v += gridDim.x * 2) {
        const float* xr = x + v * 40;
        float acc = bias;
        #pragma unroll
        for (int k = 0; k < 40; ++k) acc = fmaf(xr[k], Wx[k * 128 + c], acc);
        h[v * 128 + c] = acc;
    }
}

// ---------------- per-layer GEMM: xw(bf16) = BNrelu(in) @ Wg[l] ----------------

__global__ __launch_bounds__(256) void k_gemm(const float* __restrict__ in,
                                              const uint4* __restrict__ wt,
                                              unsigned short* __restrict__ out,
                                              const float* __restrict__ bnsc,
                                              const float* __restrict__ bnsh,
                                              int apply_bn) {
    extern __shared__ char lds[];
    char* As = lds;              // 32768 B, swizzled [row][kbyte]
    char* Bs = lds + 32768;      // 32768 B, pre-swizzled WT image

    const int tid = threadIdx.x;
    const int m0 = blockIdx.x << 7;

    { // stage WT (image already swizzled in ws): linear 32KB copy
        uint4* dst = (uint4*)Bs;
        #pragma unroll
        for (int i = 0; i < 8; ++i) dst[tid + (i << 8)] = wt[tid + (i << 8)];
    }
    { // stage A: load fp32, BN+relu, cvt bf16, swizzled ds_write
        const int c0 = (tid & 31) << 2;
        float sc0 = 1.f, sc1 = 1.f, sc2 = 1.f, sc3 = 1.f;
        float sh0 = 0.f, sh1 = 0.f, sh2 = 0.f, sh3 = 0.f;
        if (apply_bn) {
            sc0 = bnsc[c0]; sc1 = bnsc[c0 + 1]; sc2 = bnsc[c0 + 2]; sc3 = bnsc[c0 + 3];
            sh0 = bnsh[c0]; sh1 = bnsh[c0 + 1]; sh2 = bnsh[c0 + 2]; sh3 = bnsh[c0 + 3];
        }
        const int r0 = tid >> 5;
        #pragma unroll
        for (int it = 0; it < 16; ++it) {
            const int r = r0 + (it << 3);
            const int grow = m0 + r;
            float x0 = 0.f, x1 = 0.f, x2 = 0.f, x3 = 0.f;
            if (grow < NNODES) {
                const float4 v = *(const float4*)(in + grow * 128 + c0);
                x0 = v.x; x1 = v.y; x2 = v.z; x3 = v.w;
                if (apply_bn) {
                    x0 = fmaxf(fmaf(x0, sc0, sh0), 0.f);
                    x1 = fmaxf(fmaf(x1, sc1, sh1), 0.f);
                    x2 = fmaxf(fmaf(x2, sc2, sh2), 0.f);
                    x3 = fmaxf(fmaf(x3, sc3, sh3), 0.f);
                }
            }
            uint2 p;
            p.x = (unsigned int)f2bf(x0) | ((unsigned int)f2bf(x1) << 16);
            p.y = (unsigned int)f2bf(x2) | ((unsigned int)f2bf(x3) << 16);
            *(uint2*)(As + (r << 8) + (((c0 << 1)) ^ ((r & 7) << 4))) = p;
        }
    }
    __syncthreads();

    const int lane = tid & 63;
    const int wid = tid >> 6;
    const int l15 = lane & 15;
    const int lq = lane >> 4;

    const f32x4 zero = {0.f, 0.f, 0.f, 0.f};
    f32x4 acc[2][8];
    #pragma unroll
    for (int i = 0; i < 2; ++i)
        #pragma unroll
        for (int j = 0; j < 8; ++j) acc[i][j] = zero;

    #pragma unroll
    for (int kk = 0; kk < 4; ++kk) {
        const int kb = (kk << 6) + (lq << 4);
        short8 afr[2];
        #pragma unroll
        for (int rt = 0; rt < 2; ++rt) {
            const int r = (wid << 5) + (rt << 4) + l15;
            afr[rt] = *(const short8*)(As + (r << 8) + (kb ^ ((r & 7) << 4)));
        }
        #pragma unroll
        for (int ct = 0; ct < 8; ++ct) {
            const int n = (ct << 4) + l15;
            const short8 bfr = *(const short8*)(Bs + (n << 8) + (kb ^ ((n & 7) << 4)));
            acc[0][ct] = __builtin_amdgcn_mfma_f32_16x16x32_bf16(afr[0], bfr, acc[0][ct], 0, 0, 0);
            acc[1][ct] = __builtin_amdgcn_mfma_f32_16x16x32_bf16(afr[1], bfr, acc[1][ct], 0, 0, 0);
        }
    }

    #pragma unroll
    for (int rt = 0; rt < 2; ++rt) {
        #pragma unroll
        for (int j = 0; j < 4; ++j) {
            const int grow = m0 + (wid << 5) + (rt << 4) + (lq << 2) + j;
            if (grow < NNODES) {
                #pragma unroll
                for (int ct = 0; ct < 8; ++ct)
                    out[grow * 128 + (ct << 4) + l15] = f2bf(acc[rt][ct][j]);
            }
        }
    }
}

// ------- aggregation: agg_l = bg + BNrelu(prev) + D^-1/2 A D^-1/2 xw ; fused BN stats -------

__global__ __launch_bounds__(256) void k_agg(const float* __restrict__ prev,
                                             const unsigned short* __restrict__ xw,
                                             const float* __restrict__ dinv,
                                             const int* __restrict__ roff,
                                             const int* __restrict__ csrc,
                                             const float* __restrict__ cw,
                                             const float* __restrict__ bg,
                                             const float* __restrict__ bnsc,
                                             const float* __restrict__ bnsh,
                                             int apply_bn,
                                             float* __restrict__ outb,
                                             float* __restrict__ stats) {
    const int c = threadIdx.x & 127;
    const int sub = threadIdx.x >> 7;
    float sc = 1.f, sh = 0.f;
    if (apply_bn) { sc = bnsc[c]; sh = bnsh[c]; }
    const float bias = bg[c];
    float s = 0.f, s2 = 0.f;
    for (int v = blockIdx.x * 2 + sub; v < NNODES; v += gridDim.x * 2) {
        float res = prev[v * 128 + c];
        if (apply_bn) res = fmaxf(fmaf(res, sc, sh), 0.f);
        const float dv = dinv[v];
        float acc = fmaf(dv * dv, bf2f(xw[v * 128 + c]), bias + res);
        const int e0 = roff[v], e1 = roff[v + 1];
        for (int e = e0; e < e1; ++e)
            acc = fmaf(cw[e], bf2f(xw[csrc[e] * 128 + c]), acc);
        outb[v * 128 + c] = acc;
        s += acc;
        s2 = fmaf(acc, acc, s2);
    }
    __shared__ float red[256];
    red[threadIdx.x] = s; __syncthreads();
    if (sub == 0) atomicAdd(&stats[c], red[c] + red[128 + c]);
    __syncthreads();
    red[threadIdx.x] = s2; __syncthreads();
    if (sub == 0) atomicAdd(&stats[128 + c], red[c] + red[128 + c]);
}

__global__ void k_bnfin(const float* __restrict__ stats, const float* __restrict__ gamma,
                        const float* __restrict__ beta, float* __restrict__ sc,
                        float* __restrict__ sh) {
    int c = threadIdx.x;
    const float inv_n = 1.f / (float)NNODES;
    float mean = stats[c] * inv_n;
    float var = stats[128 + c] * inv_n - mean * mean;
    float s = gamma[c] * rsqrtf(var + BN_EPS);
    sc[c] = s;
    sh[c] = fmaf(-mean, s, beta[c]);
}

// ---------------- pooling (sorted batch ranges) + readout MLP ----------------

__global__ __launch_bounds__(128) void k_pool(const float* __restrict__ agg,
                                              const float* __restrict__ bnsc,
                                              const float* __restrict__ bnsh,
                                              const int* __restrict__ gstart,
                                              const float* __restrict__ W1, const float* __restrict__ b1,
                                              const float* __restrict__ W2, const float* __restrict__ b2,
                                              const float* __restrict__ W3, const float* __restrict__ b3,
                                              float* __restrict__ out) {
    __shared__ float mol[128];
    __shared__ float h1s[128];
    const int g = blockIdx.x;
    const int c = threadIdx.x;
    const float sc = bnsc[c], sh = bnsh[c];
    const int v0 = gstart[g], v1 = gstart[g + 1];
    float acc = 0.f;
    for (int v = v0; v < v1; ++v) acc += fmaf(agg[v * 128 + c], sc, sh);  // last layer: BN, no relu
    mol[c] = acc;
    __syncthreads();
    float a1 = b1[c];
    #pragma unroll 8
    for (int k = 0; k < 128; ++k) a1 = fmaf(mol[k], W1[k * 128 + c], a1);
    h1s[c] = fmaxf(a1, 0.f);
    __syncthreads();
    if (c < 64) {
        float a2 = b2[c];
        #pragma unroll 8
        for (int k = 0; k < 128; ++k) a2 = fmaf(h1s[k], W2[k * 64 + c], a2);
        float p = fmaxf(a2, 0.f) * W3[c];
        #pragma unroll
        for (int o = 32; o > 0; o >>= 1) p += __shfl_down(p, o);
        if (c == 0) out[g] = p + b3[0];
    }
}

// ---------------- launch ----------------

extern "C" void kernel_launch(void* const* d_in, const int* in_sizes, int n_in,
                              void* d_out, int out_size, void* d_ws, size_t ws_size,
                              hipStream_t stream) {
    (void)in_sizes; (void)n_in; (void)out_size; (void)ws_size;
    const float* x     = (const float*)d_in[0];
    const int*   ei    = (const int*)d_in[1];
    const int*   batch = (const int*)d_in[2];
    const float* Wx    = (const float*)d_in[3];
    const float* bx    = (const float*)d_in[4];
    const float* Wg    = (const float*)d_in[5];
    const float* bg    = (const float*)d_in[6];
    const float* gamma = (const float*)d_in[7];
    const float* beta  = (const float*)d_in[8];
    const float* W1    = (const float*)d_in[9];
    const float* b1    = (const float*)d_in[10];
    const float* W2    = (const float*)d_in[11];
    const float* b2    = (const float*)d_in[12];
    const float* W3    = (const float*)d_in[13];
    const float* b3    = (const float*)d_in[14];
    float* out = (float*)d_out;

    char* ws = (char*)d_ws;
    size_t off = 0;
    auto alloc = [&](size_t bytes) -> char* {
        char* p = ws + off;
        off += (bytes + 255) & ~(size_t)255;
        return p;
    };
    float*          aggA   = (float*)alloc((size_t)NNODES * 128 * 4);
    float*          aggB   = (float*)alloc((size_t)NNODES * 128 * 4);
    unsigned short* xw     = (unsigned short*)alloc((size_t)NNODES * 128 * 2);
    float*          dinv   = (float*)alloc((size_t)NNODES * 4);
    int*            cnt    = (int*)alloc((size_t)NNODES * 4);
    int*            cursor = (int*)alloc((size_t)NNODES * 4);
    int*            roff   = (int*)alloc((size_t)(NNODES + 1) * 4);
    int*            csrc   = (int*)alloc((size_t)NEDGES * 4);
    float*          cw     = (float*)alloc((size_t)NEDGES * 4);
    char*           wt     = alloc((size_t)NLAYERS * 32768);
    float*          stats  = (float*)alloc((size_t)NLAYERS * 256 * 4);
    float*          bnsc   = (float*)alloc((size_t)NLAYERS * 128 * 4);
    float*          bnsh   = (float*)alloc((size_t)NLAYERS * 128 * 4);
    int*            gstart = (int*)alloc((size_t)(NGRAPHS + 1) * 4);
    int*            bsum   = (int*)alloc((size_t)1024 * 4);

    const int NB = (NNODES + 255) / 256;   // 782
    const int EB = (NEDGES + 255) / 256;   // 1563
    const int GB = (NNODES + 127) / 128;   // 1563 gemm tiles

    k_init<<<NB, 256, 0, stream>>>(cnt, cursor, stats);
    k_count<<<EB, 256, 0, stream>>>(ei, cnt);
    k_dinv<<<NB, 256, 0, stream>>>(cnt, dinv);
    k_scan1<<<NB, 256, 0, stream>>>(cnt, roff, bsum);
    k_scan2<<<1, 1024, 0, stream>>>(bsum, NB);
    k_scan3<<<NB, 256, 0, stream>>>(roff, bsum);
    k_fill<<<EB, 256, 0, stream>>>(ei, dinv, roff, cursor, csrc, cw);
    k_ranges<<<NB, 256, 0, stream>>>(batch, gstart);
    k_wtrans<<<(NLAYERS * 16384 + 255) / 256, 256, 0, stream>>>(Wg, wt);
    k_inproj<<<1024, 256, 0, stream>>>(x, Wx, bx, aggA);

    float* cur = aggA;
    float* nxt = aggB;
    for (int l = 0; l < NLAYERS; ++l) {
        const float* psc = (l > 0) ? (bnsc + (l - 1) * 128) : (const float*)nullptr;
        const float* psh = (l > 0) ? (bnsh + (l - 1) * 128) : (const float*)nullptr;
        k_gemm<<<GB, 256, 65536, stream>>>(cur, (const uint4*)(wt + (size_t)l * 32768), xw,
                                           psc, psh, l > 0);
        k_agg<<<1024, 256, 0, stream>>>(cur, xw, dinv, roff, csrc, cw,
                                        bg + l * 128, psc, psh, l > 0,
                                        nxt, stats + l * 256);
        k_bnfin<<<1, 128, 0, stream>>>(stats + l * 256, gamma + l * 128, beta + l * 128,
                                       bnsc + l * 128, bnsh + l * 128);
        float* t = cur; cur = nxt; nxt = t;
    }

    k_pool<<<NGRAPHS, 128, 0, stream>>>(cur, bnsc + 4 * 128, bnsh + 4 * 128, gstart,
                                        W1, b1, W2, b2, W3, b3, out);
}

// Round 2
// 1038.042 us; speedup vs baseline: 1.3899x; 1.3899x over previous
//
#include <hip/hip_runtime.h>
#include <stdint.h>

#define NNODES  200000
#define NEDGES  400000
#define NGRAPHS 4000
#define NLAYERS 5
#define BN_EPS  1e-5f

typedef __attribute__((ext_vector_type(8))) short short8;
typedef __attribute__((ext_vector_type(4))) float f32x4;

__device__ __forceinline__ unsigned short f2bf(float f) {
    unsigned int u = __float_as_uint(f);
    return (unsigned short)((u + 0x7fffu + ((u >> 16) & 1u)) >> 16);
}
__device__ __forceinline__ float bf2f(unsigned short b) {
    return __uint_as_float(((unsigned int)b) << 16);
}

// ---------------- graph prep ----------------

__global__ void k_init(int* __restrict__ cnt, int* __restrict__ cursor, float* __restrict__ stats) {
    int i = blockIdx.x * 256 + threadIdx.x;
    if (i < NNODES) { cnt[i] = 0; cursor[i] = 0; }
    if (i < NLAYERS * 256) stats[i] = 0.f;
}

__global__ void k_count(const int* __restrict__ ei, int* __restrict__ cnt) {
    int e = blockIdx.x * 256 + threadIdx.x;
    if (e < NEDGES) atomicAdd(&cnt[ei[NEDGES + e]], 1);
}

__global__ void k_dinv(const int* __restrict__ cnt, float* __restrict__ dinv) {
    int v = blockIdx.x * 256 + threadIdx.x;
    if (v < NNODES) dinv[v] = rsqrtf((float)cnt[v] + 1.0f);
}

__global__ __launch_bounds__(256) void k_scan1(const int* __restrict__ cnt,
                                               int* __restrict__ roff, int* __restrict__ bsum) {
    __shared__ int s[256];
    int t = threadIdx.x;
    int v = blockIdx.x * 256 + t;
    int val = (v < NNODES) ? cnt[v] : 0;
    s[t] = val; __syncthreads();
    int sum = val;
    for (int o = 1; o < 256; o <<= 1) {
        int tmp = (t >= o) ? s[t - o] : 0;
        __syncthreads();
        sum += tmp; s[t] = sum;
        __syncthreads();
    }
    if (v < NNODES) roff[v] = sum - val;       // exclusive within block
    if (t == 255) bsum[blockIdx.x] = s[255];
}

__global__ __launch_bounds__(1024) void k_scan2(int* __restrict__ bsum, int nb) {
    __shared__ int s[1024];
    int t = threadIdx.x;
    int val = (t < nb) ? bsum[t] : 0;
    s[t] = val; __syncthreads();
    int sum = val;
    for (int o = 1; o < 1024; o <<= 1) {
        int tmp = (t >= o) ? s[t - o] : 0;
        __syncthreads();
        sum += tmp; s[t] = sum;
        __syncthreads();
    }
    if (t < nb) bsum[t] = sum - val;           // exclusive block offsets
}

__global__ void k_scan3(int* __restrict__ roff, const int* __restrict__ bsum) {
    int v = blockIdx.x * 256 + threadIdx.x;
    if (v < NNODES) roff[v] += bsum[blockIdx.x];
    if (v == 0) roff[NNODES] = NEDGES;
}

__global__ void k_fill(const int* __restrict__ ei, const float* __restrict__ dinv,
                       const int* __restrict__ roff, int* __restrict__ cursor,
                       int* __restrict__ csrc, float* __restrict__ cw) {
    int e = blockIdx.x * 256 + threadIdx.x;
    if (e >= NEDGES) return;
    int s = ei[e], d = ei[NEDGES + e];
    int pos = atomicAdd(&cursor[d], 1);
    int idx = roff[d] + pos;
    csrc[idx] = s;
    cw[idx] = dinv[s] * dinv[d];
}

__global__ void k_ranges(const int* __restrict__ batch, int* __restrict__ gstart) {
    int v = blockIdx.x * 256 + threadIdx.x;
    if (v >= NNODES) return;
    int b = batch[v];
    if (v == 0) {
        for (int g = 0; g <= b; ++g) gstart[g] = 0;
    } else {
        int pb = batch[v - 1];
        for (int g = pb + 1; g <= b; ++g) gstart[g] = v;
    }
    if (v == NNODES - 1) {
        for (int g = b + 1; g <= NGRAPHS; ++g) gstart[g] = NNODES;
    }
}

// transpose + bf16-convert + LDS-image-swizzle the 5 layer weights: WT[n][k] = W[k][n]
__global__ void k_wtrans(const float* __restrict__ Wg, char* __restrict__ wt) {
    int idx = blockIdx.x * 256 + threadIdx.x;
    if (idx >= NLAYERS * 128 * 128) return;
    int l = idx >> 14;
    int rem = idx & 16383;
    int n = rem >> 7;
    int k = rem & 127;
    float v = Wg[l * 16384 + k * 128 + n];
    char* img = wt + l * 32768;
    *(unsigned short*)(img + (n << 8) + (((k << 1)) ^ ((n & 7) << 4))) = f2bf(v);
}

// ---------------- input projection: h0 = x @ Wx + bx ----------------
// Wx column cached in 40 registers per thread; 4 nodes in flight (independent FMA chains).

__global__ __launch_bounds__(256) void k_inproj(const float* __restrict__ x,
                                                const float* __restrict__ Wx,
                                                const float* __restrict__ bx,
                                                float* __restrict__ h) {
    const int c = threadIdx.x & 127;
    const int sub = threadIdx.x >> 7;
    float wcol[40];
    #pragma unroll
    for (int k = 0; k < 40; ++k) wcol[k] = Wx[k * 128 + c];
    const float bias = bx[c];
    const int stride = gridDim.x * 8;          // 2 subgroups * 4 nodes
    for (int base = (blockIdx.x * 2 + sub) * 4; base < NNODES; base += stride) {
        // NNODES % 4 == 0, so all 4 nodes valid whenever base < NNODES
        float a0 = bias, a1 = bias, a2 = bias, a3 = bias;
        const float* r0 = x + (size_t)base * 40;
        #pragma unroll
        for (int q = 0; q < 10; ++q) {
            const float4 v0 = ((const float4*)r0)[q];
            const float4 v1 = ((const float4*)(r0 + 40))[q];
            const float4 v2 = ((const float4*)(r0 + 80))[q];
            const float4 v3 = ((const float4*)(r0 + 120))[q];
            const int k = q << 2;
            a0 = fmaf(v0.x, wcol[k], a0);     a1 = fmaf(v1.x, wcol[k], a1);
            a2 = fmaf(v2.x, wcol[k], a2);     a3 = fmaf(v3.x, wcol[k], a3);
            a0 = fmaf(v0.y, wcol[k + 1], a0); a1 = fmaf(v1.y, wcol[k + 1], a1);
            a2 = fmaf(v2.y, wcol[k + 1], a2); a3 = fmaf(v3.y, wcol[k + 1], a3);
            a0 = fmaf(v0.z, wcol[k + 2], a0); a1 = fmaf(v1.z, wcol[k + 2], a1);
            a2 = fmaf(v2.z, wcol[k + 2], a2); a3 = fmaf(v3.z, wcol[k + 2], a3);
            a0 = fmaf(v0.w, wcol[k + 3], a0); a1 = fmaf(v1.w, wcol[k + 3], a1);
            a2 = fmaf(v2.w, wcol[k + 3], a2); a3 = fmaf(v3.w, wcol[k + 3], a3);
        }
        h[(size_t)(base + 0) * 128 + c] = a0;
        h[(size_t)(base + 1) * 128 + c] = a1;
        h[(size_t)(base + 2) * 128 + c] = a2;
        h[(size_t)(base + 3) * 128 + c] = a3;
    }
}

// ---------------- per-layer GEMM: xw(bf16) = BNrelu(in) @ Wg[l] ----------------

__global__ __launch_bounds__(256) void k_gemm(const float* __restrict__ in,
                                              const uint4* __restrict__ wt,
                                              unsigned short* __restrict__ out,
                                              const float* __restrict__ bnsc,
                                              const float* __restrict__ bnsh,
                                              int apply_bn) {
    extern __shared__ char lds[];
    char* As = lds;              // 32768 B, swizzled [row][kbyte]
    char* Bs = lds + 32768;      // 32768 B, pre-swizzled WT image

    const int tid = threadIdx.x;
    const int m0 = blockIdx.x << 7;

    { // stage WT (image already swizzled in ws): linear 32KB copy
        uint4* dst = (uint4*)Bs;
        #pragma unroll
        for (int i = 0; i < 8; ++i) dst[tid + (i << 8)] = wt[tid + (i << 8)];
    }
    { // stage A: load fp32, BN+relu, cvt bf16, swizzled ds_write
        const int c0 = (tid & 31) << 2;
        float sc0 = 1.f, sc1 = 1.f, sc2 = 1.f, sc3 = 1.f;
        float sh0 = 0.f, sh1 = 0.f, sh2 = 0.f, sh3 = 0.f;
        if (apply_bn) {
            sc0 = bnsc[c0]; sc1 = bnsc[c0 + 1]; sc2 = bnsc[c0 + 2]; sc3 = bnsc[c0 + 3];
            sh0 = bnsh[c0]; sh1 = bnsh[c0 + 1]; sh2 = bnsh[c0 + 2]; sh3 = bnsh[c0 + 3];
        }
        const int r0 = tid >> 5;
        #pragma unroll
        for (int it = 0; it < 16; ++it) {
            const int r = r0 + (it << 3);
            const int grow = m0 + r;
            float x0 = 0.f, x1 = 0.f, x2 = 0.f, x3 = 0.f;
            if (grow < NNODES) {
                const float4 v = *(const float4*)(in + (size_t)grow * 128 + c0);
                x0 = v.x; x1 = v.y; x2 = v.z; x3 = v.w;
                if (apply_bn) {
                    x0 = fmaxf(fmaf(x0, sc0, sh0), 0.f);
                    x1 = fmaxf(fmaf(x1, sc1, sh1), 0.f);
                    x2 = fmaxf(fmaf(x2, sc2, sh2), 0.f);
                    x3 = fmaxf(fmaf(x3, sc3, sh3), 0.f);
                }
            }
            uint2 p;
            p.x = (unsigned int)f2bf(x0) | ((unsigned int)f2bf(x1) << 16);
            p.y = (unsigned int)f2bf(x2) | ((unsigned int)f2bf(x3) << 16);
            *(uint2*)(As + (r << 8) + (((c0 << 1)) ^ ((r & 7) << 4))) = p;
        }
    }
    __syncthreads();

    const int lane = tid & 63;
    const int wid = tid >> 6;
    const int l15 = lane & 15;
    const int lq = lane >> 4;

    const f32x4 zero = {0.f, 0.f, 0.f, 0.f};
    f32x4 acc[2][8];
    #pragma unroll
    for (int i = 0; i < 2; ++i)
        #pragma unroll
        for (int j = 0; j < 8; ++j) acc[i][j] = zero;

    #pragma unroll
    for (int kk = 0; kk < 4; ++kk) {
        const int kb = (kk << 6) + (lq << 4);
        short8 afr[2];
        #pragma unroll
        for (int rt = 0; rt < 2; ++rt) {
            const int r = (wid << 5) + (rt << 4) + l15;
            afr[rt] = *(const short8*)(As + (r << 8) + (kb ^ ((r & 7) << 4)));
        }
        #pragma unroll
        for (int ct = 0; ct < 8; ++ct) {
            const int n = (ct << 4) + l15;
            const short8 bfr = *(const short8*)(Bs + (n << 8) + (kb ^ ((n & 7) << 4)));
            acc[0][ct] = __builtin_amdgcn_mfma_f32_16x16x32_bf16(afr[0], bfr, acc[0][ct], 0, 0, 0);
            acc[1][ct] = __builtin_amdgcn_mfma_f32_16x16x32_bf16(afr[1], bfr, acc[1][ct], 0, 0, 0);
        }
    }

    #pragma unroll
    for (int rt = 0; rt < 2; ++rt) {
        #pragma unroll
        for (int j = 0; j < 4; ++j) {
            const int grow = m0 + (wid << 5) + (rt << 4) + (lq << 2) + j;
            if (grow < NNODES) {
                #pragma unroll
                for (int ct = 0; ct < 8; ++ct)
                    out[(size_t)grow * 128 + (ct << 4) + l15] = f2bf(acc[rt][ct][j]);
            }
        }
    }
}

// ------- aggregation: agg_l = bg + BNrelu(prev) + D^-1/2 A D^-1/2 xw ; fused BN stats -------
// 64 lanes per node (2 channels each, ushort2 gathers); edge loop unrolled x2 with
// prefetched indices so both gathers are in flight; grid 2048 for 8 waves/SIMD.

__global__ __launch_bounds__(256) void k_agg(const float* __restrict__ prev,
                                             const unsigned short* __restrict__ xw,
                                             const float* __restrict__ dinv,
                                             const int* __restrict__ roff,
                                             const int* __restrict__ csrc,
                                             const float* __restrict__ cw,
                                             const float* __restrict__ bg,
                                             const float* __restrict__ bnsc,
                                             const float* __restrict__ bnsh,
                                             int apply_bn,
                                             float* __restrict__ outb,
                                             float* __restrict__ stats) {
    const int lane = threadIdx.x & 63;
    const int slot = threadIdx.x >> 6;          // 4 node-slots per block
    const int c2 = lane << 1;                   // channels c2, c2+1
    float sc0 = 1.f, sc1 = 1.f, sh0 = 0.f, sh1 = 0.f;
    if (apply_bn) {
        sc0 = bnsc[c2]; sc1 = bnsc[c2 + 1];
        sh0 = bnsh[c2]; sh1 = bnsh[c2 + 1];
    }
    const float b0 = bg[c2], b1 = bg[c2 + 1];
    float s0 = 0.f, s1 = 0.f, q0 = 0.f, q1 = 0.f;
    const int stride = gridDim.x * 4;
    for (int v = blockIdx.x * 4 + slot; v < NNODES; v += stride) {
        const float2 res = *(const float2*)(prev + (size_t)v * 128 + c2);
        float a0, a1;
        if (apply_bn) {
            a0 = b0 + fmaxf(fmaf(res.x, sc0, sh0), 0.f);
            a1 = b1 + fmaxf(fmaf(res.y, sc1, sh1), 0.f);
        } else {
            a0 = b0 + res.x;
            a1 = b1 + res.y;
        }
        const unsigned int self = *(const unsigned int*)(xw + (size_t)v * 128 + c2);
        const float dv = dinv[v];
        const float dvv = dv * dv;
        a0 = fmaf(dvv, bf2f((unsigned short)(self & 0xffffu)), a0);
        a1 = fmaf(dvv, bf2f((unsigned short)(self >> 16)), a1);
        int e = roff[v];
        const int e1 = roff[v + 1];
        for (; e + 2 <= e1; e += 2) {
            const int sA = csrc[e], sB = csrc[e + 1];
            const float wA = cw[e], wB = cw[e + 1];
            const unsigned int gA = *(const unsigned int*)(xw + (size_t)sA * 128 + c2);
            const unsigned int gB = *(const unsigned int*)(xw + (size_t)sB * 128 + c2);
            a0 = fmaf(wA, bf2f((unsigned short)(gA & 0xffffu)), a0);
            a1 = fmaf(wA, bf2f((unsigned short)(gA >> 16)), a1);
            a0 = fmaf(wB, bf2f((unsigned short)(gB & 0xffffu)), a0);
            a1 = fmaf(wB, bf2f((unsigned short)(gB >> 16)), a1);
        }
        if (e < e1) {
            const int sA = csrc[e];
            const float wA = cw[e];
            const unsigned int gA = *(const unsigned int*)(xw + (size_t)sA * 128 + c2);
            a0 = fmaf(wA, bf2f((unsigned short)(gA & 0xffffu)), a0);
            a1 = fmaf(wA, bf2f((unsigned short)(gA >> 16)), a1);
        }
        float2 o; o.x = a0; o.y = a1;
        *(float2*)(outb + (size_t)v * 128 + c2) = o;
        s0 += a0; s1 += a1;
        q0 = fmaf(a0, a0, q0); q1 = fmaf(a1, a1, q1);
    }
    __shared__ float red[512];
    red[slot * 128 + c2] = s0; red[slot * 128 + c2 + 1] = s1;
    __syncthreads();
    if (threadIdx.x < 128) {
        const int ch = threadIdx.x;
        atomicAdd(&stats[ch], red[ch] + red[128 + ch] + red[256 + ch] + red[384 + ch]);
    }
    __syncthreads();
    red[slot * 128 + c2] = q0; red[slot * 128 + c2 + 1] = q1;
    __syncthreads();
    if (threadIdx.x < 128) {
        const int ch = threadIdx.x;
        atomicAdd(&stats[128 + ch], red[ch] + red[128 + ch] + red[256 + ch] + red[384 + ch]);
    }
}

__global__ void k_bnfin(const float* __restrict__ stats, const float* __restrict__ gamma,
                        const float* __restrict__ beta, float* __restrict__ sc,
                        float* __restrict__ sh) {
    int c = threadIdx.x;
    const float inv_n = 1.f / (float)NNODES;
    float mean = stats[c] * inv_n;
    float var = stats[128 + c] * inv_n - mean * mean;
    float s = gamma[c] * rsqrtf(var + BN_EPS);
    sc[c] = s;
    sh[c] = fmaf(-mean, s, beta[c]);
}

// ---------------- pooling (sorted batch ranges) + readout MLP ----------------

__global__ __launch_bounds__(128) void k_pool(const float* __restrict__ agg,
                                              const float* __restrict__ bnsc,
                                              const float* __restrict__ bnsh,
                                              const int* __restrict__ gstart,
                                              const float* __restrict__ W1, const float* __restrict__ b1,
                                              const float* __restrict__ W2, const float* __restrict__ b2,
                                              const float* __restrict__ W3, const float* __restrict__ b3,
                                              float* __restrict__ out) {
    __shared__ float mol[128];
    __shared__ float h1s[128];
    const int g = blockIdx.x;
    const int c = threadIdx.x;
    const float sc = bnsc[c], sh = bnsh[c];
    const int v0 = gstart[g], v1 = gstart[g + 1];
    float acc = 0.f;
    for (int v = v0; v < v1; ++v) acc += fmaf(agg[(size_t)v * 128 + c], sc, sh);  // last layer: BN, no relu
    mol[c] = acc;
    __syncthreads();
    float a1 = b1[c];
    #pragma unroll 8
    for (int k = 0; k < 128; ++k) a1 = fmaf(mol[k], W1[k * 128 + c], a1);
    h1s[c] = fmaxf(a1, 0.f);
    __syncthreads();
    if (c < 64) {
        float a2 = b2[c];
        #pragma unroll 8
        for (int k = 0; k < 128; ++k) a2 = fmaf(h1s[k], W2[k * 64 + c], a2);
        float p = fmaxf(a2, 0.f) * W3[c];
        #pragma unroll
        for (int o = 32; o > 0; o >>= 1) p += __shfl_down(p, o);
        if (c == 0) out[g] = p + b3[0];
    }
}

// ---------------- launch ----------------

extern "C" void kernel_launch(void* const* d_in, const int* in_sizes, int n_in,
                              void* d_out, int out_size, void* d_ws, size_t ws_size,
                              hipStream_t stream) {
    (void)in_sizes; (void)n_in; (void)out_size; (void)ws_size;
    const float* x     = (const float*)d_in[0];
    const int*   ei    = (const int*)d_in[1];
    const int*   batch = (const int*)d_in[2];
    const float* Wx    = (const float*)d_in[3];
    const float* bx    = (const float*)d_in[4];
    const float* Wg    = (const float*)d_in[5];
    const float* bg    = (const float*)d_in[6];
    const float* gamma = (const float*)d_in[7];
    const float* beta  = (const float*)d_in[8];
    const float* W1    = (const float*)d_in[9];
    const float* b1    = (const float*)d_in[10];
    const float* W2    = (const float*)d_in[11];
    const float* b2    = (const float*)d_in[12];
    const float* W3    = (const float*)d_in[13];
    const float* b3    = (const float*)d_in[14];
    float* out = (float*)d_out;

    char* ws = (char*)d_ws;
    size_t off = 0;
    auto alloc = [&](size_t bytes) -> char* {
        char* p = ws + off;
        off += (bytes + 255) & ~(size_t)255;
        return p;
    };
    float*          aggA   = (float*)alloc((size_t)NNODES * 128 * 4);
    float*          aggB   = (float*)alloc((size_t)NNODES * 128 * 4);
    unsigned short* xw     = (unsigned short*)alloc((size_t)NNODES * 128 * 2);
    float*          dinv   = (float*)alloc((size_t)NNODES * 4);
    int*            cnt    = (int*)alloc((size_t)NNODES * 4);
    int*            cursor = (int*)alloc((size_t)NNODES * 4);
    int*            roff   = (int*)alloc((size_t)(NNODES + 1) * 4);
    int*            csrc   = (int*)alloc((size_t)NEDGES * 4);
    float*          cw     = (float*)alloc((size_t)NEDGES * 4);
    char*           wt     = alloc((size_t)NLAYERS * 32768);
    float*          stats  = (float*)alloc((size_t)NLAYERS * 256 * 4);
    float*          bnsc   = (float*)alloc((size_t)NLAYERS * 128 * 4);
    float*          bnsh   = (float*)alloc((size_t)NLAYERS * 128 * 4);
    int*            gstart = (int*)alloc((size_t)(NGRAPHS + 1) * 4);
    int*            bsum   = (int*)alloc((size_t)1024 * 4);

    const int NB = (NNODES + 255) / 256;   // 782
    const int EB = (NEDGES + 255) / 256;   // 1563
    const int GB = (NNODES + 127) / 128;   // 1563 gemm tiles

    k_init<<<NB, 256, 0, stream>>>(cnt, cursor, stats);
    k_count<<<EB, 256, 0, stream>>>(ei, cnt);
    k_dinv<<<NB, 256, 0, stream>>>(cnt, dinv);
    k_scan1<<<NB, 256, 0, stream>>>(cnt, roff, bsum);
    k_scan2<<<1, 1024, 0, stream>>>(bsum, NB);
    k_scan3<<<NB, 256, 0, stream>>>(roff, bsum);
    k_fill<<<EB, 256, 0, stream>>>(ei, dinv, roff, cursor, csrc, cw);
    k_ranges<<<NB, 256, 0, stream>>>(batch, gstart);
    k_wtrans<<<(NLAYERS * 16384 + 255) / 256, 256, 0, stream>>>(Wg, wt);
    k_inproj<<<2048, 256, 0, stream>>>(x, Wx, bx, aggA);

    float* cur = aggA;
    float* nxt = aggB;
    for (int l = 0; l < NLAYERS; ++l) {
        const float* psc = (l > 0) ? (bnsc + (l - 1) * 128) : (const float*)nullptr;
        const float* psh = (l > 0) ? (bnsh + (l - 1) * 128) : (const float*)nullptr;
        k_gemm<<<GB, 256, 65536, stream>>>(cur, (const uint4*)(wt + (size_t)l * 32768), xw,
                                           psc, psh, l > 0);
        k_agg<<<2048, 256, 0, stream>>>(cur, xw, dinv, roff, csrc, cw,
                                        bg + l * 128, psc, psh, l > 0,
                                        nxt, stats + l * 256);
        k_bnfin<<<1, 128, 0, stream>>>(stats + l * 256, gamma + l * 128, beta + l * 128,
                                       bnsc + l * 128, bnsh + l * 128);
        float* t = cur; cur = nxt; nxt = t;
    }

    k_pool<<<NGRAPHS, 128, 0, stream>>>(cur, bnsc + 4 * 128, bnsh + 4 * 128, gstart,
                                        W1, b1, W2, b2, W3, b3, out);
}

// Round 3
// 850.467 us; speedup vs baseline: 1.6964x; 1.2206x over previous
//
#include <hip/hip_runtime.h>
#include <stdint.h>

#define NNODES  200000
#define NEDGES  400000
#define NGRAPHS 4000
#define NLAYERS 5
#define BN_EPS  1e-5f

typedef __attribute__((ext_vector_type(8))) short short8;
typedef __attribute__((ext_vector_type(4))) float f32x4;

__device__ __forceinline__ unsigned int f2bf(float f) {
    unsigned int u = __float_as_uint(f);
    return (u + 0x7fffu + ((u >> 16) & 1u)) >> 16;
}
__device__ __forceinline__ float bf2f(unsigned int b) {
    return __uint_as_float(b << 16);
}

// ---------------- graph prep ----------------

__global__ void k_init(int* __restrict__ cnt, int* __restrict__ cursor, float* __restrict__ stats) {
    int i = blockIdx.x * 256 + threadIdx.x;
    if (i < NNODES) { cnt[i] = 0; cursor[i] = 0; }
    if (i < NLAYERS * 256) stats[i] = 0.f;
}

__global__ void k_count(const int* __restrict__ ei, int* __restrict__ cnt) {
    int e = blockIdx.x * 256 + threadIdx.x;
    if (e < NEDGES) atomicAdd(&cnt[ei[NEDGES + e]], 1);
}

__global__ void k_dinv(const int* __restrict__ cnt, float* __restrict__ dinv) {
    int v = blockIdx.x * 256 + threadIdx.x;
    if (v < NNODES) dinv[v] = rsqrtf((float)cnt[v] + 1.0f);
}

__global__ __launch_bounds__(256) void k_scan1(const int* __restrict__ cnt,
                                               int* __restrict__ roff, int* __restrict__ bsum) {
    __shared__ int s[256];
    int t = threadIdx.x;
    int v = blockIdx.x * 256 + t;
    int val = (v < NNODES) ? cnt[v] : 0;
    s[t] = val; __syncthreads();
    int sum = val;
    for (int o = 1; o < 256; o <<= 1) {
        int tmp = (t >= o) ? s[t - o] : 0;
        __syncthreads();
        sum += tmp; s[t] = sum;
        __syncthreads();
    }
    if (v < NNODES) roff[v] = sum - val;       // exclusive within block
    if (t == 255) bsum[blockIdx.x] = s[255];
}

__global__ __launch_bounds__(1024) void k_scan2(int* __restrict__ bsum, int nb) {
    __shared__ int s[1024];
    int t = threadIdx.x;
    int val = (t < nb) ? bsum[t] : 0;
    s[t] = val; __syncthreads();
    int sum = val;
    for (int o = 1; o < 1024; o <<= 1) {
        int tmp = (t >= o) ? s[t - o] : 0;
        __syncthreads();
        sum += tmp; s[t] = sum;
        __syncthreads();
    }
    if (t < nb) bsum[t] = sum - val;           // exclusive block offsets
}

__global__ void k_scan3(int* __restrict__ roff, const int* __restrict__ bsum) {
    int v = blockIdx.x * 256 + threadIdx.x;
    if (v < NNODES) roff[v] += bsum[blockIdx.x];
    if (v == 0) roff[NNODES] = NEDGES;
}

__global__ void k_fill(const int* __restrict__ ei, const float* __restrict__ dinv,
                       const int* __restrict__ roff, int* __restrict__ cursor,
                       int* __restrict__ csrc, float* __restrict__ cw) {
    int e = blockIdx.x * 256 + threadIdx.x;
    if (e >= NEDGES) return;
    int s = ei[e], d = ei[NEDGES + e];
    int pos = atomicAdd(&cursor[d], 1);
    int idx = roff[d] + pos;
    csrc[idx] = s;
    cw[idx] = dinv[s] * dinv[d];
}

__global__ void k_ranges(const int* __restrict__ batch, int* __restrict__ gstart) {
    int v = blockIdx.x * 256 + threadIdx.x;
    if (v >= NNODES) return;
    int b = batch[v];
    if (v == 0) {
        for (int g = 0; g <= b; ++g) gstart[g] = 0;
    } else {
        int pb = batch[v - 1];
        for (int g = pb + 1; g <= b; ++g) gstart[g] = v;
    }
    if (v == NNODES - 1) {
        for (int g = b + 1; g <= NGRAPHS; ++g) gstart[g] = NNODES;
    }
}

// transpose + bf16-convert + swizzle layer weights WT[n][k]=W[k][n] (256B rows),
// and Wx -> WxT[n][k0..63] zero-padded (128B rows).
__global__ void k_wtrans(const float* __restrict__ Wg, const float* __restrict__ Wx,
                         char* __restrict__ wt, char* __restrict__ wxt) {
    int idx = blockIdx.x * 256 + threadIdx.x;
    if (idx < NLAYERS * 16384) {
        int l = idx >> 14;
        int rem = idx & 16383;
        int n = rem >> 7;
        int k = rem & 127;
        float v = Wg[l * 16384 + k * 128 + n];
        char* img = wt + l * 32768;
        *(unsigned short*)(img + (n << 8) + ((k << 1) ^ ((n & 7) << 4))) = (unsigned short)f2bf(v);
    } else if (idx < NLAYERS * 16384 + 8192) {
        int j = idx - NLAYERS * 16384;
        int n = j >> 6;
        int k = j & 63;
        float v = (k < 40) ? Wx[k * 128 + n] : 0.f;
        *(unsigned short*)(wxt + (n << 7) + ((k << 1) ^ ((n & 7) << 4))) = (unsigned short)f2bf(v);
    }
}

// ---------------- input projection (MFMA): h0 = bf16(x @ Wx + bx) ----------------
// K=40 zero-padded to 64; A rows 128B in LDS; same slot-XOR swizzle family as k_gemm.

__global__ __launch_bounds__(256) void k_inproj(const float* __restrict__ x,
                                                const uint4* __restrict__ wxt,
                                                const float* __restrict__ bx,
                                                unsigned short* __restrict__ out) {
    extern __shared__ char lds[];
    char* As = lds;              // 128 rows * 128 B
    char* Bs = lds + 16384;      // WxT image, 16 KB

    const int tid = threadIdx.x;
    const int m0 = blockIdx.x << 7;

    { // stage WxT (pre-swizzled): 16 KB linear copy
        uint4* dst = (uint4*)Bs;
        #pragma unroll
        for (int i = 0; i < 4; ++i) dst[tid + (i << 8)] = wxt[tid + (i << 8)];
    }
    { // stage A: 16 threads per row cover k 0..63 (4 each), zero-pad k>=40
        const int kq = (tid & 15) << 2;   // 0,4,...,60
        const int r0 = tid >> 4;          // 0..15
        #pragma unroll
        for (int it = 0; it < 8; ++it) {
            const int r = r0 + (it << 4);
            const int grow = m0 + r;
            float x0 = 0.f, x1 = 0.f, x2 = 0.f, x3 = 0.f;
            if (kq < 40 && grow < NNODES) {
                const float4 v = *(const float4*)(x + (size_t)grow * 40 + kq);
                x0 = v.x; x1 = v.y; x2 = v.z; x3 = v.w;
            }
            uint2 p;
            p.x = f2bf(x0) | (f2bf(x1) << 16);
            p.y = f2bf(x2) | (f2bf(x3) << 16);
            *(uint2*)(As + (r << 7) + ((kq << 1) ^ ((r & 7) << 4))) = p;
        }
    }
    __syncthreads();

    const int lane = tid & 63;
    const int wid = tid >> 6;
    const int l15 = lane & 15;
    const int lq = lane >> 4;

    const f32x4 zero = {0.f, 0.f, 0.f, 0.f};
    f32x4 acc[2][8];
    #pragma unroll
    for (int i = 0; i < 2; ++i)
        #pragma unroll
        for (int j = 0; j < 8; ++j) acc[i][j] = zero;

    #pragma unroll
    for (int kk = 0; kk < 2; ++kk) {
        const int kb = (kk << 6) + (lq << 4);
        short8 afr[2];
        #pragma unroll
        for (int rt = 0; rt < 2; ++rt) {
            const int r = (wid << 5) + (rt << 4) + l15;
            afr[rt] = *(const short8*)(As + (r << 7) + (kb ^ ((r & 7) << 4)));
        }
        #pragma unroll
        for (int ct = 0; ct < 8; ++ct) {
            const int n = (ct << 4) + l15;
            const short8 bfr = *(const short8*)(Bs + (n << 7) + (kb ^ ((n & 7) << 4)));
            acc[0][ct] = __builtin_amdgcn_mfma_f32_16x16x32_bf16(afr[0], bfr, acc[0][ct], 0, 0, 0);
            acc[1][ct] = __builtin_amdgcn_mfma_f32_16x16x32_bf16(afr[1], bfr, acc[1][ct], 0, 0, 0);
        }
    }

    float biasv[8];
    #pragma unroll
    for (int ct = 0; ct < 8; ++ct) biasv[ct] = bx[(ct << 4) + l15];

    #pragma unroll
    for (int rt = 0; rt < 2; ++rt) {
        #pragma unroll
        for (int j = 0; j < 4; ++j) {
            const int grow = m0 + (wid << 5) + (rt << 4) + (lq << 2) + j;
            if (grow < NNODES) {
                #pragma unroll
                for (int ct = 0; ct < 8; ++ct)
                    out[(size_t)grow * 128 + (ct << 4) + l15] =
                        (unsigned short)f2bf(acc[rt][ct][j] + biasv[ct]);
            }
        }
    }
}

// ---------------- per-layer GEMM: xw(bf16) = BNrelu(in_bf16) @ Wg[l] ----------------

__global__ __launch_bounds__(256) void k_gemm(const unsigned short* __restrict__ in,
                                              const uint4* __restrict__ wt,
                                              unsigned short* __restrict__ out,
                                              const float* __restrict__ bnsc,
                                              const float* __restrict__ bnsh,
                                              int apply_bn) {
    extern __shared__ char lds[];
    char* As = lds;              // 32768 B, swizzled [row][kbyte], 256B rows
    char* Bs = lds + 32768;      // 32768 B, pre-swizzled WT image

    const int tid = threadIdx.x;
    const int m0 = blockIdx.x << 7;

    { // stage WT: linear 32KB copy
        uint4* dst = (uint4*)Bs;
        #pragma unroll
        for (int i = 0; i < 8; ++i) dst[tid + (i << 8)] = wt[tid + (i << 8)];
    }
    { // stage A: load bf16, BN+relu in fp32, back to bf16, swizzled ds_write
        const int c0 = (tid & 31) << 2;
        float sc0 = 1.f, sc1 = 1.f, sc2 = 1.f, sc3 = 1.f;
        float sh0 = 0.f, sh1 = 0.f, sh2 = 0.f, sh3 = 0.f;
        if (apply_bn) {
            sc0 = bnsc[c0]; sc1 = bnsc[c0 + 1]; sc2 = bnsc[c0 + 2]; sc3 = bnsc[c0 + 3];
            sh0 = bnsh[c0]; sh1 = bnsh[c0 + 1]; sh2 = bnsh[c0 + 2]; sh3 = bnsh[c0 + 3];
        }
        const int r0 = tid >> 5;
        #pragma unroll
        for (int it = 0; it < 16; ++it) {
            const int r = r0 + (it << 3);
            const int grow = m0 + r;
            uint2 p = {0u, 0u};
            if (grow < NNODES) {
                const uint2 raw = *(const uint2*)(in + (size_t)grow * 128 + c0);
                if (apply_bn) {
                    float x0 = fmaxf(fmaf(bf2f(raw.x & 0xffffu), sc0, sh0), 0.f);
                    float x1 = fmaxf(fmaf(bf2f(raw.x >> 16),     sc1, sh1), 0.f);
                    float x2 = fmaxf(fmaf(bf2f(raw.y & 0xffffu), sc2, sh2), 0.f);
                    float x3 = fmaxf(fmaf(bf2f(raw.y >> 16),     sc3, sh3), 0.f);
                    p.x = f2bf(x0) | (f2bf(x1) << 16);
                    p.y = f2bf(x2) | (f2bf(x3) << 16);
                } else {
                    p = raw;   // already bf16
                }
            }
            *(uint2*)(As + (r << 8) + ((c0 << 1) ^ ((r & 7) << 4))) = p;
        }
    }
    __syncthreads();

    const int lane = tid & 63;
    const int wid = tid >> 6;
    const int l15 = lane & 15;
    const int lq = lane >> 4;

    const f32x4 zero = {0.f, 0.f, 0.f, 0.f};
    f32x4 acc[2][8];
    #pragma unroll
    for (int i = 0; i < 2; ++i)
        #pragma unroll
        for (int j = 0; j < 8; ++j) acc[i][j] = zero;

    #pragma unroll
    for (int kk = 0; kk < 4; ++kk) {
        const int kb = (kk << 6) + (lq << 4);
        short8 afr[2];
        #pragma unroll
        for (int rt = 0; rt < 2; ++rt) {
            const int r = (wid << 5) + (rt << 4) + l15;
            afr[rt] = *(const short8*)(As + (r << 8) + (kb ^ ((r & 7) << 4)));
        }
        #pragma unroll
        for (int ct = 0; ct < 8; ++ct) {
            const int n = (ct << 4) + l15;
            const short8 bfr = *(const short8*)(Bs + (n << 8) + (kb ^ ((n & 7) << 4)));
            acc[0][ct] = __builtin_amdgcn_mfma_f32_16x16x32_bf16(afr[0], bfr, acc[0][ct], 0, 0, 0);
            acc[1][ct] = __builtin_amdgcn_mfma_f32_16x16x32_bf16(afr[1], bfr, acc[1][ct], 0, 0, 0);
        }
    }

    #pragma unroll
    for (int rt = 0; rt < 2; ++rt) {
        #pragma unroll
        for (int j = 0; j < 4; ++j) {
            const int grow = m0 + (wid << 5) + (rt << 4) + (lq << 2) + j;
            if (grow < NNODES) {
                #pragma unroll
                for (int ct = 0; ct < 8; ++ct)
                    out[(size_t)grow * 128 + (ct << 4) + l15] =
                        (unsigned short)f2bf(acc[rt][ct][j]);
            }
        }
    }
}

// ------- aggregation: agg_l = bg + BNrelu(prev) + D^-1/2 A D^-1/2 xw ; fused BN stats -------
// bf16 activations; node metadata software-pipelined one iteration ahead.

__global__ __launch_bounds__(256) void k_agg(const unsigned short* __restrict__ prev,
                                             const unsigned short* __restrict__ xw,
                                             const float* __restrict__ dinv,
                                             const int* __restrict__ roff,
                                             const int* __restrict__ csrc,
                                             const float* __restrict__ cw,
                                             const float* __restrict__ bg,
                                             const float* __restrict__ bnsc,
                                             const float* __restrict__ bnsh,
                                             int apply_bn,
                                             unsigned short* __restrict__ outb,
                                             float* __restrict__ stats) {
    const int lane = threadIdx.x & 63;
    const int slot = threadIdx.x >> 6;          // 4 node-slots per block
    const int c2 = lane << 1;                   // channels c2, c2+1
    float sc0 = 1.f, sc1 = 1.f, sh0 = 0.f, sh1 = 0.f;
    if (apply_bn) {
        sc0 = bnsc[c2]; sc1 = bnsc[c2 + 1];
        sh0 = bnsh[c2]; sh1 = bnsh[c2 + 1];
    }
    const float b0 = bg[c2], b1 = bg[c2 + 1];
    float s0 = 0.f, s1 = 0.f, q0 = 0.f, q1 = 0.f;
    const int stride = gridDim.x * 4;

    int v = blockIdx.x * 4 + slot;
    int rof0 = 0, rof1 = 0; unsigned int resu = 0, selfu = 0; float dv = 0.f;
    if (v < NNODES) {
        rof0 = roff[v]; rof1 = roff[v + 1];
        resu  = *(const unsigned int*)(prev + (size_t)v * 128 + c2);
        selfu = *(const unsigned int*)(xw + (size_t)v * 128 + c2);
        dv = dinv[v];
    }
    while (v < NNODES) {
        const int vn = v + stride;
        int n_rof0 = 0, n_rof1 = 0; unsigned int n_res = 0, n_self = 0; float n_dv = 0.f;
        if (vn < NNODES) {   // prefetch next node's metadata before the edge chain
            n_rof0 = roff[vn]; n_rof1 = roff[vn + 1];
            n_res  = *(const unsigned int*)(prev + (size_t)vn * 128 + c2);
            n_self = *(const unsigned int*)(xw + (size_t)vn * 128 + c2);
            n_dv = dinv[vn];
        }
        float a0, a1;
        {
            const float r0f = bf2f(resu & 0xffffu);
            const float r1f = bf2f(resu >> 16);
            if (apply_bn) {
                a0 = b0 + fmaxf(fmaf(r0f, sc0, sh0), 0.f);
                a1 = b1 + fmaxf(fmaf(r1f, sc1, sh1), 0.f);
            } else {
                a0 = b0 + r0f;
                a1 = b1 + r1f;
            }
            const float dvv = dv * dv;
            a0 = fmaf(dvv, bf2f(selfu & 0xffffu), a0);
            a1 = fmaf(dvv, bf2f(selfu >> 16), a1);
        }
        int e = rof0;
        for (; e + 2 <= rof1; e += 2) {
            const int sA = csrc[e], sB = csrc[e + 1];
            const float wA = cw[e], wB = cw[e + 1];
            const unsigned int gA = *(const unsigned int*)(xw + (size_t)sA * 128 + c2);
            const unsigned int gB = *(const unsigned int*)(xw + (size_t)sB * 128 + c2);
            a0 = fmaf(wA, bf2f(gA & 0xffffu), a0);
            a1 = fmaf(wA, bf2f(gA >> 16), a1);
            a0 = fmaf(wB, bf2f(gB & 0xffffu), a0);
            a1 = fmaf(wB, bf2f(gB >> 16), a1);
        }
        if (e < rof1) {
            const int sA = csrc[e];
            const float wA = cw[e];
            const unsigned int gA = *(const unsigned int*)(xw + (size_t)sA * 128 + c2);
            a0 = fmaf(wA, bf2f(gA & 0xffffu), a0);
            a1 = fmaf(wA, bf2f(gA >> 16), a1);
        }
        *(unsigned int*)(outb + (size_t)v * 128 + c2) = f2bf(a0) | (f2bf(a1) << 16);
        s0 += a0; s1 += a1;
        q0 = fmaf(a0, a0, q0); q1 = fmaf(a1, a1, q1);
        v = vn; rof0 = n_rof0; rof1 = n_rof1; resu = n_res; selfu = n_self; dv = n_dv;
    }
    __shared__ float red[512];
    red[slot * 128 + c2] = s0; red[slot * 128 + c2 + 1] = s1;
    __syncthreads();
    if (threadIdx.x < 128) {
        const int ch = threadIdx.x;
        atomicAdd(&stats[ch], red[ch] + red[128 + ch] + red[256 + ch] + red[384 + ch]);
    }
    __syncthreads();
    red[slot * 128 + c2] = q0; red[slot * 128 + c2 + 1] = q1;
    __syncthreads();
    if (threadIdx.x < 128) {
        const int ch = threadIdx.x;
        atomicAdd(&stats[128 + ch], red[ch] + red[128 + ch] + red[256 + ch] + red[384 + ch]);
    }
}

__global__ void k_bnfin(const float* __restrict__ stats, const float* __restrict__ gamma,
                        const float* __restrict__ beta, float* __restrict__ sc,
                        float* __restrict__ sh) {
    int c = threadIdx.x;
    const float inv_n = 1.f / (float)NNODES;
    float mean = stats[c] * inv_n;
    float var = stats[128 + c] * inv_n - mean * mean;
    float s = gamma[c] * rsqrtf(var + BN_EPS);
    sc[c] = s;
    sh[c] = fmaf(-mean, s, beta[c]);
}

// ---------------- pooling (sorted batch ranges) + readout MLP ----------------

__global__ __launch_bounds__(128) void k_pool(const unsigned short* __restrict__ agg,
                                              const float* __restrict__ bnsc,
                                              const float* __restrict__ bnsh,
                                              const int* __restrict__ gstart,
                                              const float* __restrict__ W1, const float* __restrict__ b1,
                                              const float* __restrict__ W2, const float* __restrict__ b2,
                                              const float* __restrict__ W3, const float* __restrict__ b3,
                                              float* __restrict__ out) {
    __shared__ float mol[128];
    __shared__ float h1s[128];
    const int g = blockIdx.x;
    const int c = threadIdx.x;
    const float sc = bnsc[c], sh = bnsh[c];
    const int v0 = gstart[g], v1 = gstart[g + 1];
    float acc = 0.f;
    for (int v = v0; v < v1; ++v)
        acc += fmaf(bf2f(agg[(size_t)v * 128 + c]), sc, sh);  // last layer: BN, no relu
    mol[c] = acc;
    __syncthreads();
    float a1 = b1[c];
    #pragma unroll 8
    for (int k = 0; k < 128; ++k) a1 = fmaf(mol[k], W1[k * 128 + c], a1);
    h1s[c] = fmaxf(a1, 0.f);
    __syncthreads();
    if (c < 64) {
        float a2 = b2[c];
        #pragma unroll 8
        for (int k = 0; k < 128; ++k) a2 = fmaf(h1s[k], W2[k * 64 + c], a2);
        float p = fmaxf(a2, 0.f) * W3[c];
        #pragma unroll
        for (int o = 32; o > 0; o >>= 1) p += __shfl_down(p, o);
        if (c == 0) out[g] = p + b3[0];
    }
}

// ---------------- launch ----------------

extern "C" void kernel_launch(void* const* d_in, const int* in_sizes, int n_in,
                              void* d_out, int out_size, void* d_ws, size_t ws_size,
                              hipStream_t stream) {
    (void)in_sizes; (void)n_in; (void)out_size; (void)ws_size;
    const float* x     = (const float*)d_in[0];
    const int*   ei    = (const int*)d_in[1];
    const int*   batch = (const int*)d_in[2];
    const float* Wx    = (const float*)d_in[3];
    const float* bx    = (const float*)d_in[4];
    const float* Wg    = (const float*)d_in[5];
    const float* bg    = (const float*)d_in[6];
    const float* gamma = (const float*)d_in[7];
    const float* beta  = (const float*)d_in[8];
    const float* W1    = (const float*)d_in[9];
    const float* b1    = (const float*)d_in[10];
    const float* W2    = (const float*)d_in[11];
    const float* b2    = (const float*)d_in[12];
    const float* W3    = (const float*)d_in[13];
    const float* b3    = (const float*)d_in[14];
    float* out = (float*)d_out;

    char* ws = (char*)d_ws;
    size_t off = 0;
    auto alloc = [&](size_t bytes) -> char* {
        char* p = ws + off;
        off += (bytes + 255) & ~(size_t)255;
        return p;
    };
    unsigned short* aggA   = (unsigned short*)alloc((size_t)NNODES * 128 * 2);
    unsigned short* aggB   = (unsigned short*)alloc((size_t)NNODES * 128 * 2);
    unsigned short* xw     = (unsigned short*)alloc((size_t)NNODES * 128 * 2);
    float*          dinv   = (float*)alloc((size_t)NNODES * 4);
    int*            cnt    = (int*)alloc((size_t)NNODES * 4);
    int*            cursor = (int*)alloc((size_t)NNODES * 4);
    int*            roff   = (int*)alloc((size_t)(NNODES + 1) * 4);
    int*            csrc   = (int*)alloc((size_t)NEDGES * 4);
    float*          cw     = (float*)alloc((size_t)NEDGES * 4);
    char*           wt     = alloc((size_t)NLAYERS * 32768);
    char*           wxt    = alloc((size_t)16384);
    float*          stats  = (float*)alloc((size_t)NLAYERS * 256 * 4);
    float*          bnsc   = (float*)alloc((size_t)NLAYERS * 128 * 4);
    float*          bnsh   = (float*)alloc((size_t)NLAYERS * 128 * 4);
    int*            gstart = (int*)alloc((size_t)(NGRAPHS + 1) * 4);
    int*            bsum   = (int*)alloc((size_t)1024 * 4);

    const int NB = (NNODES + 255) / 256;   // 782
    const int EB = (NEDGES + 255) / 256;   // 1563
    const int GB = (NNODES + 127) / 128;   // 1563 gemm tiles
    const int WB = (NLAYERS * 16384 + 8192 + 255) / 256;

    k_init<<<NB, 256, 0, stream>>>(cnt, cursor, stats);
    k_count<<<EB, 256, 0, stream>>>(ei, cnt);
    k_dinv<<<NB, 256, 0, stream>>>(cnt, dinv);
    k_scan1<<<NB, 256, 0, stream>>>(cnt, roff, bsum);
    k_scan2<<<1, 1024, 0, stream>>>(bsum, NB);
    k_scan3<<<NB, 256, 0, stream>>>(roff, bsum);
    k_fill<<<EB, 256, 0, stream>>>(ei, dinv, roff, cursor, csrc, cw);
    k_ranges<<<NB, 256, 0, stream>>>(batch, gstart);
    k_wtrans<<<WB, 256, 0, stream>>>(Wg, Wx, wt, wxt);
    k_inproj<<<GB, 256, 32768, stream>>>(x, (const uint4*)wxt, bx, aggA);

    unsigned short* cur = aggA;
    unsigned short* nxt = aggB;
    for (int l = 0; l < NLAYERS; ++l) {
        const float* psc = (l > 0) ? (bnsc + (l - 1) * 128) : (const float*)nullptr;
        const float* psh = (l > 0) ? (bnsh + (l - 1) * 128) : (const float*)nullptr;
        k_gemm<<<GB, 256, 65536, stream>>>(cur, (const uint4*)(wt + (size_t)l * 32768), xw,
                                           psc, psh, l > 0);
        k_agg<<<2048, 256, 0, stream>>>(cur, xw, dinv, roff, csrc, cw,
                                        bg + l * 128, psc, psh, l > 0,
                                        nxt, stats + l * 256);
        k_bnfin<<<1, 128, 0, stream>>>(stats + l * 256, gamma + l * 128, beta + l * 128,
                                       bnsc + l * 128, bnsh + l * 128);
        unsigned short* t = cur; cur = nxt; nxt = t;
    }

    k_pool<<<NGRAPHS, 128, 0, stream>>>(cur, bnsc + 4 * 128, bnsh + 4 * 128, gstart,
                                        W1, b1, W2, b2, W3, b3, out);
}